// Round 15
// baseline (564.613 us; speedup 1.0000x reference)
//
#include <hip/hip_runtime.h>

#define HID 128

typedef __attribute__((ext_vector_type(8))) short bf16x8;
typedef __attribute__((ext_vector_type(4))) float f32x4;

__device__ inline unsigned short f2bf(float f) {
    unsigned u = __float_as_uint(f);
    unsigned r = (u + 0x7fff + ((u >> 16) & 1)) >> 16;
    return (unsigned short)r;
}
__device__ inline float bf2f(unsigned short b) {
    return __uint_as_float(((unsigned)b) << 16);
}
// split v into trunc-bf16 hi (low 16 bits) + trunc-bf16 lo (high 16 bits)
__device__ inline unsigned packhl(float v) {
    unsigned h = __float_as_uint(v) >> 16;
    float lo = v - __uint_as_float(h << 16);
    unsigned l = __float_as_uint(lo) >> 16;
    return h | (l << 16);
}

// ================= CSR build =================
__global__ void hist_kernel(const int* __restrict__ dst, int* __restrict__ cnt, int E)
{
    int e = blockIdx.x * blockDim.x + threadIdx.x;
    if (e < E) atomicAdd(&cnt[dst[e]], 1);
}

__global__ void scan_block(const int* __restrict__ cnt, int* __restrict__ excl,
                           int* __restrict__ partials, int Nn)
{
    __shared__ int ls[256];
    int i = blockIdx.x * 256 + threadIdx.x;
    int v = (i < Nn) ? cnt[i] : 0;
    ls[threadIdx.x] = v;
    __syncthreads();
    for (int off = 1; off < 256; off <<= 1) {
        int t = (threadIdx.x >= off) ? ls[threadIdx.x - off] : 0;
        __syncthreads();
        ls[threadIdx.x] += t;
        __syncthreads();
    }
    if (i < Nn) excl[i] = ls[threadIdx.x] - v;
    if (threadIdx.x == 255) partials[blockIdx.x] = ls[255];
}

__global__ void scan_partials(int* __restrict__ partials, int nb, int* __restrict__ offsets,
                              int Nn, int E)
{
    __shared__ int ls[256];
    int t = threadIdx.x;
    int v = (t < nb) ? partials[t] : 0;
    ls[t] = v;
    __syncthreads();
    for (int off = 1; off < 256; off <<= 1) {
        int x = (t >= off) ? ls[t - off] : 0;
        __syncthreads();
        ls[t] += x;
        __syncthreads();
    }
    if (t < nb) partials[t] = ls[t] - v;
    if (t == 0) offsets[Nn] = E;
}

__global__ void scan_add(const int* __restrict__ excl, const int* __restrict__ partials,
                         int* __restrict__ offsets, int* __restrict__ cursor, int Nn)
{
    int i = blockIdx.x * 256 + threadIdx.x;
    if (i < Nn) {
        int o = excl[i] + partials[blockIdx.x];
        offsets[i] = o;
        cursor[i] = o;
    }
}

__global__ void fill_kernel(const int* __restrict__ dst, const int* __restrict__ src,
                            const float* __restrict__ ea, int* __restrict__ cursor,
                            float4* __restrict__ epack, int E)
{
    int e = blockIdx.x * blockDim.x + threadIdx.x;
    if (e < E) {
        int pos = atomicAdd(&cursor[dst[e]], 1);
        float4 p;
        p.x = __int_as_float(src[e]);
        p.y = ea[e * 3];
        p.z = ea[e * 3 + 1];
        p.w = ea[e * 3 + 2];
        epack[pos] = p;
    }
}

// ======= W precompute: transpose + hi/lo bf16 split: Wt[n][k] from W[k][n] =======
__global__ void wsplit(const float* __restrict__ W, unsigned short* __restrict__ wh,
                       unsigned short* __restrict__ wl)
{
    int idx = blockIdx.x * 256 + threadIdx.x;
    int n = idx >> 7, k = idx & 127;
    float w = W[k * 128 + n];
    unsigned short h = (unsigned short)(__float_as_uint(w) >> 16);
    float lo = w - bf2f(h);
    unsigned short l = (unsigned short)(__float_as_uint(lo) >> 16);
    wh[idx] = h;
    wl[idx] = l;
}

// ================= layer 1: CSR gather (dim 7) =================
__global__ void gather_d7(const float* __restrict__ x, const float4* __restrict__ epack,
                          const int* __restrict__ offsets,
                          const float* __restrict__ We, const float* __restrict__ be,
                          float* __restrict__ agg, int Nn)
{
    int tid = blockIdx.x * blockDim.x + threadIdx.x;
    int node = tid >> 3;
    int c = tid & 7;
    if (node >= Nn) return;
    float w0 = 0.f, w1 = 0.f, w2 = 0.f, b = 0.f;
    if (c < 7) { w0 = We[c]; w1 = We[7 + c]; w2 = We[14 + c]; b = be[c]; }
    int beg = offsets[node], end = offsets[node + 1];
    float acc = 0.f;
    for (int i = beg; i < end; ++i) {
        float4 ep = epack[i];
        int s = __float_as_int(ep.x);
        float v = b;
        v = fmaf(ep.y, w0, v);
        v = fmaf(ep.z, w1, v);
        v = fmaf(ep.w, w2, v);
        if (c < 7) v += x[s * 7 + c];
        acc += fmaxf(v, 0.f);
    }
    if (c < 7) agg[node * 7 + c] = acc;
}

// ===== layers 2/3: gather; 2 waves per node (edge-split), 4x unroll per wave =====
// block: 256 thr = 4 waves = 2 nodes. Wave half 0: edges [beg,mid); half 1: [mid,end).
// Partials combined via LDS; wave 0 adds self-term h (coalesced fp32) and writes.
__global__ void gather_d128(const unsigned short* __restrict__ h16,
                            const float4* __restrict__ epack,
                            const int* __restrict__ offsets,
                            const float* __restrict__ We, const float* __restrict__ be,
                            const float* __restrict__ hprev,
                            float* __restrict__ agg, int Nn)
{
    __shared__ float part[2][128];
    int t = threadIdx.x;
    int wave = t >> 6;
    int lane = t & 63;
    int local = wave >> 1;     // node slot in block (0/1)
    int half = wave & 1;       // edge-half
    int node = blockIdx.x * 2 + local;
    bool ok = node < Nn;
    int beg = 0, end = 0;
    if (ok) { beg = offsets[node]; end = offsets[node + 1]; }
    int mid = beg + (((end - beg) + 1) >> 1);
    int lo = half ? mid : beg;
    int hi = half ? end : mid;

    const float2* W2 = (const float2*)We;
    float2 w0 = W2[lane];
    float2 w1 = W2[64 + lane];
    float2 w2 = W2[128 + lane];
    float2 bb = ((const float2*)be)[lane];
    float accx = 0.f, accy = 0.f;

    int i = lo;
    for (; i + 4 <= hi; i += 4) {
        float4 e0 = epack[i], e1 = epack[i + 1], e2 = epack[i + 2], e3 = epack[i + 3];
        ushort2 p0 = ((const ushort2*)(h16 + (size_t)__float_as_int(e0.x) * HID))[lane];
        ushort2 p1 = ((const ushort2*)(h16 + (size_t)__float_as_int(e1.x) * HID))[lane];
        ushort2 p2 = ((const ushort2*)(h16 + (size_t)__float_as_int(e2.x) * HID))[lane];
        ushort2 p3 = ((const ushort2*)(h16 + (size_t)__float_as_int(e3.x) * HID))[lane];
        float vx, vy;
        vx = bb.x + bf2f(p0.x);
        vx = fmaf(e0.y, w0.x, vx); vx = fmaf(e0.z, w1.x, vx); vx = fmaf(e0.w, w2.x, vx);
        vy = bb.y + bf2f(p0.y);
        vy = fmaf(e0.y, w0.y, vy); vy = fmaf(e0.z, w1.y, vy); vy = fmaf(e0.w, w2.y, vy);
        accx += fmaxf(vx, 0.f); accy += fmaxf(vy, 0.f);
        vx = bb.x + bf2f(p1.x);
        vx = fmaf(e1.y, w0.x, vx); vx = fmaf(e1.z, w1.x, vx); vx = fmaf(e1.w, w2.x, vx);
        vy = bb.y + bf2f(p1.y);
        vy = fmaf(e1.y, w0.y, vy); vy = fmaf(e1.z, w1.y, vy); vy = fmaf(e1.w, w2.y, vy);
        accx += fmaxf(vx, 0.f); accy += fmaxf(vy, 0.f);
        vx = bb.x + bf2f(p2.x);
        vx = fmaf(e2.y, w0.x, vx); vx = fmaf(e2.z, w1.x, vx); vx = fmaf(e2.w, w2.x, vx);
        vy = bb.y + bf2f(p2.y);
        vy = fmaf(e2.y, w0.y, vy); vy = fmaf(e2.z, w1.y, vy); vy = fmaf(e2.w, w2.y, vy);
        accx += fmaxf(vx, 0.f); accy += fmaxf(vy, 0.f);
        vx = bb.x + bf2f(p3.x);
        vx = fmaf(e3.y, w0.x, vx); vx = fmaf(e3.z, w1.x, vx); vx = fmaf(e3.w, w2.x, vx);
        vy = bb.y + bf2f(p3.y);
        vy = fmaf(e3.y, w0.y, vy); vy = fmaf(e3.z, w1.y, vy); vy = fmaf(e3.w, w2.y, vy);
        accx += fmaxf(vx, 0.f); accy += fmaxf(vy, 0.f);
    }
    for (; i < hi; ++i) {
        float4 ep = epack[i];
        ushort2 hp = ((const ushort2*)(h16 + (size_t)__float_as_int(ep.x) * HID))[lane];
        float vx = bb.x + bf2f(hp.x);
        vx = fmaf(ep.y, w0.x, vx); vx = fmaf(ep.z, w1.x, vx); vx = fmaf(ep.w, w2.x, vx);
        float vy = bb.y + bf2f(hp.y);
        vy = fmaf(ep.y, w0.y, vy); vy = fmaf(ep.z, w1.y, vy); vy = fmaf(ep.w, w2.y, vy);
        accx += fmaxf(vx, 0.f);
        accy += fmaxf(vy, 0.f);
    }
    if (half == 1) {
        float2 pv = {accx, accy};
        ((float2*)part[local])[lane] = pv;
    }
    __syncthreads();
    if (half == 0 && ok) {
        float2 other = ((float2*)part[local])[lane];
        float2 hv = ((const float2*)(hprev + (size_t)node * HID))[lane];
        float2 outv = {accx + other.x + hv.x, accy + other.y + hv.y};
        ((float2*)(agg + (size_t)node * HID))[lane] = outv;
    }
}

// ===== MFMA core: acc[2][4] = T(64 rows packed hi/lo) @ Wt for this wave's 32 cols =====
__device__ __forceinline__ void mfma_core(
    const unsigned* T,
    const unsigned short* __restrict__ Wh, const unsigned short* __restrict__ Wl,
    const float* __restrict__ bias,
    int wave, int q, int li, f32x4 (&acc)[2][4])
{
    int ctg0 = wave * 2, ctg1 = wave * 2 + 1;
    float b0 = bias[ctg0 * 16 + li];
    float b1v = bias[ctg1 * 16 + li];
#pragma unroll
    for (int rf = 0; rf < 4; ++rf) {
        acc[0][rf][0] = b0;  acc[0][rf][1] = b0;  acc[0][rf][2] = b0;  acc[0][rf][3] = b0;
        acc[1][rf][0] = b1v; acc[1][rf][1] = b1v; acc[1][rf][2] = b1v; acc[1][rf][3] = b1v;
    }
#pragma unroll
    for (int kb = 0; kb < 4; ++kb) {
        int k0 = kb * 32 + q * 8;
        size_t w0off = (size_t)(ctg0 * 16 + li) * HID + k0;
        size_t w1off = (size_t)(ctg1 * 16 + li) * HID + k0;
        bf16x8 bh0 = *(const bf16x8*)(Wh + w0off);
        bf16x8 bl0 = *(const bf16x8*)(Wl + w0off);
        bf16x8 bh1 = *(const bf16x8*)(Wh + w1off);
        bf16x8 bl1 = *(const bf16x8*)(Wl + w1off);
#pragma unroll
        for (int rf = 0; rf < 4; ++rf) {
            const unsigned* Tp = T + (rf * 16 + li) * 132 + k0;
            uint4 pa = *(const uint4*)Tp;
            uint4 pb = *(const uint4*)(Tp + 4);
            unsigned pv[8] = {pa.x, pa.y, pa.z, pa.w, pb.x, pb.y, pb.z, pb.w};
            bf16x8 ah, al;
#pragma unroll
            for (int j = 0; j < 8; ++j) {
                ah[j] = (short)(pv[j] & 0xffffu);
                al[j] = (short)(pv[j] >> 16);
            }
            acc[0][rf] = __builtin_amdgcn_mfma_f32_16x16x32_bf16(ah, bh0, acc[0][rf], 0, 0, 0);
            acc[0][rf] = __builtin_amdgcn_mfma_f32_16x16x32_bf16(ah, bl0, acc[0][rf], 0, 0, 0);
            acc[0][rf] = __builtin_amdgcn_mfma_f32_16x16x32_bf16(al, bh0, acc[0][rf], 0, 0, 0);
            acc[1][rf] = __builtin_amdgcn_mfma_f32_16x16x32_bf16(ah, bh1, acc[1][rf], 0, 0, 0);
            acc[1][rf] = __builtin_amdgcn_mfma_f32_16x16x32_bf16(ah, bl1, acc[1][rf], 0, 0, 0);
            acc[1][rf] = __builtin_amdgcn_mfma_f32_16x16x32_bf16(al, bh1, acc[1][rf], 0, 0, 0);
        }
    }
}

// global epilogue: write C (+optional relu, +optional BN stats via wave-owned cols)
template <bool RELU, bool STATS>
__device__ __forceinline__ void epilogue_global(
    f32x4 (&acc)[2][4], float* __restrict__ C, float* __restrict__ bnsums,
    float* sls, float* slq, int node0, int wave, int q, int li, int t, int N)
{
#pragma unroll
    for (int ct = 0; ct < 2; ++ct) {
        int colb = (wave * 2 + ct) * 16 + li;
        float sv = 0.f, qv = 0.f;
#pragma unroll
        for (int rf = 0; rf < 4; ++rf) {
#pragma unroll
            for (int r = 0; r < 4; ++r) {
                int n = node0 + rf * 16 + q * 4 + r;
                float v = acc[ct][rf][r];
                if (RELU) v = fmaxf(v, 0.f);
                if (n < N) {
                    C[(size_t)n * HID + colb] = v;
                    if (STATS) { sv += v; qv = fmaf(v, v, qv); }
                }
            }
        }
        if (STATS) {
            sv += __shfl_down(sv, 16); sv += __shfl_down(sv, 32);
            qv += __shfl_down(qv, 16); qv += __shfl_down(qv, 32);
            if (q == 0) { sls[colb] = sv; slq[colb] = qv; }
        }
    }
    if (STATS) {
        __syncthreads();
        if (t < 128) {
            atomicAdd(&bnsums[t], sls[t]);
            atomicAdd(&bnsums[128 + t], slq[t]);
        }
    }
}

// ===== fused MLP layers 2/3 =====
template <bool RELU, bool STATS>
__global__ __launch_bounds__(256) void mlp128_fused(
    const float* __restrict__ A,
    const unsigned short* __restrict__ W1h, const unsigned short* __restrict__ W1l,
    const float* __restrict__ b1,
    const unsigned short* __restrict__ W2h, const unsigned short* __restrict__ W2l,
    const float* __restrict__ b2,
    float* __restrict__ C, float* __restrict__ bnsums, int N)
{
    __shared__ unsigned Ta[64 * 132];
    __shared__ unsigned Tb[64 * 132];
    __shared__ float sls[128], slq[128];
    int t = threadIdx.x;
    int wave = t >> 6, lane = t & 63;
    int q = lane >> 4, li = lane & 15;
    int node0 = blockIdx.x * 64;

    {
        const float4* A4 = (const float4*)(A + (size_t)node0 * HID);
        int rows = N - node0 < 64 ? (N - node0) : 64;
        int limit4 = 32 * rows;
#pragma unroll
        for (int i = 0; i < 8; ++i) {
            int idx = t + i * 256;
            float4 v = {0.f, 0.f, 0.f, 0.f};
            if (idx < limit4) v = A4[idx];
            int row = idx >> 5, c4 = idx & 31;
            uint4 pk;
            pk.x = packhl(v.x); pk.y = packhl(v.y);
            pk.z = packhl(v.z); pk.w = packhl(v.w);
            *(uint4*)(Ta + row * 132 + c4 * 4) = pk;
        }
    }
    __syncthreads();

    {
        f32x4 acc[2][4];
        mfma_core(Ta, W1h, W1l, b1, wave, q, li, acc);
#pragma unroll
        for (int ct = 0; ct < 2; ++ct) {
            int colb = (wave * 2 + ct) * 16 + li;
#pragma unroll
            for (int rf = 0; rf < 4; ++rf) {
#pragma unroll
                for (int r = 0; r < 4; ++r) {
                    float v = fmaxf(acc[ct][rf][r], 0.f);
                    Tb[(rf * 16 + q * 4 + r) * 132 + colb] = packhl(v);
                }
            }
        }
    }
    __syncthreads();

    {
        f32x4 acc[2][4];
        mfma_core(Tb, W2h, W2l, b2, wave, q, li, acc);
        epilogue_global<RELU, STATS>(acc, C, bnsums, sls, slq, node0, wave, q, li, t, N);
    }
}

// ===== fused MLP layer 1 =====
template <bool RELU, bool STATS>
__global__ __launch_bounds__(256) void mlp1_fused(
    const float* __restrict__ x, const float* __restrict__ agg,
    const float* __restrict__ W1, const float* __restrict__ b1,     // [7][128]
    const unsigned short* __restrict__ W2h, const unsigned short* __restrict__ W2l,
    const float* __restrict__ b2,
    float* __restrict__ C, float* __restrict__ bnsums, int N)
{
    __shared__ unsigned Tb[64 * 132];
    __shared__ float sls[128], slq[128];
    int t = threadIdx.x;
    int wave = t >> 6, lane = t & 63;
    int q = lane >> 4, li = lane & 15;
    int node0 = blockIdx.x * 64;

    {
        int row = node0 + wave * 16 + li;
        bool ok = row < N;
        float xa[7];
#pragma unroll
        for (int k = 0; k < 7; ++k) xa[k] = ok ? (x[row * 7 + k] + agg[row * 7 + k]) : 0.f;
        const float4* W14 = (const float4*)W1;
        const float4* b14 = (const float4*)b1;
        unsigned* Trow = Tb + (wave * 16 + li) * 132 + q * 32;
#pragma unroll
        for (int c4 = 0; c4 < 8; ++c4) {
            float4 v = b14[q * 8 + c4];
#pragma unroll
            for (int k = 0; k < 7; ++k) {
                float4 w = W14[k * 32 + q * 8 + c4];
                v.x = fmaf(xa[k], w.x, v.x);
                v.y = fmaf(xa[k], w.y, v.y);
                v.z = fmaf(xa[k], w.z, v.z);
                v.w = fmaf(xa[k], w.w, v.w);
            }
            uint4 pk;
            pk.x = packhl(fmaxf(v.x, 0.f));
            pk.y = packhl(fmaxf(v.y, 0.f));
            pk.z = packhl(fmaxf(v.z, 0.f));
            pk.w = packhl(fmaxf(v.w, 0.f));
            *(uint4*)(Trow + c4 * 4) = pk;
        }
    }
    __syncthreads();

    {
        f32x4 acc[2][4];
        mfma_core(Tb, W2h, W2l, b2, wave, q, li, acc);
        epilogue_global<RELU, STATS>(acc, C, bnsums, sls, slq, node0, wave, q, li, t, N);
    }
}

// ================= BN =================
__global__ void bn_finalize(const float* __restrict__ sums, const float* __restrict__ g,
                            const float* __restrict__ bt, float* __restrict__ ab, int N)
{
    int c = threadIdx.x;
    if (c < 128) {
        float inv = 1.f / (float)N;
        float mu = sums[c] * inv;
        float var = sums[128 + c] * inv - mu * mu;
        float rs = rsqrtf(fmaxf(var, 0.f) + 1e-5f);
        float a = g[c] * rs;
        ab[c] = a;
        ab[128 + c] = bt[c] - a * mu;
    }
}

template <bool W16>
__global__ void bn_apply_relu(const float* __restrict__ h, const float* __restrict__ ab,
                              float* __restrict__ out, unsigned short* __restrict__ h16,
                              long long total)
{
    long long i = ((long long)blockIdx.x * blockDim.x + threadIdx.x) * 2;
    if (i >= total) return;
    int c = (int)(i & 127);
    float2 hv = *(const float2*)(h + i);
    float v0 = fmaxf(fmaf(hv.x, ab[c], ab[128 + c]), 0.f);
    float v1 = fmaxf(fmaf(hv.y, ab[c + 1], ab[129 + c]), 0.f);
    float2 ov = {v0, v1};
    *(float2*)(out + i) = ov;
    if (W16) {
        unsigned pair = (unsigned)f2bf(v0) | ((unsigned)f2bf(v1) << 16);
        *(unsigned*)(h16 + i) = pair;
    }
}

// ================= fused layer-3 BN-apply + mean-pool scatter =================
__global__ void bn_pool(const float* __restrict__ agg, const float* __restrict__ ab,
                        const int* __restrict__ batch,
                        float* __restrict__ pools, float* __restrict__ cnt, int N)
{
    long long i = (long long)blockIdx.x * blockDim.x + threadIdx.x;
    long long total = (long long)N * HID;
    if (i >= total) return;
    int n = (int)(i >> 7);
    int c = (int)(i & 127);
    int g = batch[n];
    float v = fmaxf(fmaf(agg[i], ab[c], ab[128 + c]), 0.f);
    atomicAdd(&pools[(long long)g * HID + c], v);
    if (c == 0) atomicAdd(&cnt[g], 1.f);
}

__global__ void head_kernel(const float* __restrict__ pools, const float* __restrict__ cnt,
                            const float* __restrict__ Wf1, const float* __restrict__ bf1,
                            const float* __restrict__ Wf2, const float* __restrict__ bf2,
                            float* __restrict__ out, int G)
{
    int g = blockIdx.x;
    int t = threadIdx.x;
    __shared__ float p[128];
    float inv = 1.f / fmaxf(cnt[g], 1.f);
    p[t] = pools[g * 128 + t] * inv;
    p[t + 64] = pools[g * 128 + t + 64] * inv;
    __syncthreads();
    float o = bf1[t];
#pragma unroll 8
    for (int k = 0; k < 128; ++k) o = fmaf(p[k], Wf1[k * 64 + t], o);
    o = fmaxf(o, 0.f);
    float prod = o * Wf2[t];
#pragma unroll
    for (int off = 32; off > 0; off >>= 1) prod += __shfl_down(prod, off);
    if (t == 0) out[g] = prod + bf2[0];
}

extern "C" void kernel_launch(void* const* d_in, const int* in_sizes, int n_in,
                              void* d_out, int out_size, void* d_ws, size_t ws_size,
                              hipStream_t stream)
{
    const float* x     = (const float*)d_in[0];
    const float* ea    = (const float*)d_in[1];
    const int*   eidx  = (const int*)d_in[2];
    const int*   batch = (const int*)d_in[3];
    const float* We1 = (const float*)d_in[4];  const float* be1 = (const float*)d_in[5];
    const float* W11 = (const float*)d_in[6];  const float* b11 = (const float*)d_in[7];
    const float* W12 = (const float*)d_in[8];  const float* b12 = (const float*)d_in[9];
    const float* g1  = (const float*)d_in[10]; const float* bt1 = (const float*)d_in[11];
    const float* We2 = (const float*)d_in[12]; const float* be2 = (const float*)d_in[13];
    const float* W21 = (const float*)d_in[14]; const float* b21 = (const float*)d_in[15];
    const float* W22 = (const float*)d_in[16]; const float* b22 = (const float*)d_in[17];
    const float* g2  = (const float*)d_in[18]; const float* bt2 = (const float*)d_in[19];
    const float* We3 = (const float*)d_in[20]; const float* be3 = (const float*)d_in[21];
    const float* W31 = (const float*)d_in[22]; const float* b31 = (const float*)d_in[23];
    const float* W32 = (const float*)d_in[24]; const float* b32 = (const float*)d_in[25];
    const float* g3  = (const float*)d_in[26]; const float* bt3 = (const float*)d_in[27];
    const float* Wf1 = (const float*)d_in[28]; const float* bf1 = (const float*)d_in[29];
    const float* Wf2 = (const float*)d_in[30]; const float* bf2 = (const float*)d_in[31];

    const int N = in_sizes[0] / 7;
    const int E = in_sizes[1] / 3;
    const int G = out_size;
    const int* src = eidx;
    const int* dst = eidx + E;

    float* ws = (float*)d_ws;
    float* buf_h   = ws;                          // N*128
    float* buf_agg = buf_h + (size_t)N * HID;     // N*128
    float* buf_t   = buf_agg + (size_t)N * HID;   // N*128
    float* bnsums  = buf_t + (size_t)N * HID;     // 256
    float* bnab    = bnsums + 256;                // 256
    float* pools   = bnab + 256;                  // G*128
    float* cntp    = pools + (size_t)G * HID;     // G
    float4* epack  = (float4*)(cntp + G);         // E float4
    unsigned short* h16 = (unsigned short*)(epack + E);  // N*128 bf16
    int*   icnt    = (int*)(h16 + (size_t)N * HID); // N
    int*   ioffs   = icnt + N;                    // N+1
    int*   icur    = ioffs + N + 1;               // N
    int*   ipart   = icur + N;                    // 256
    int*   iexcl   = ipart + 256;                 // N
    unsigned short* wt = (unsigned short*)(iexcl + N);  // 5 x 2 x 16384
    unsigned short* w12h = wt;            unsigned short* w12l = wt + 16384;
    unsigned short* w21h = wt + 32768;    unsigned short* w21l = wt + 49152;
    unsigned short* w22h = wt + 65536;    unsigned short* w22l = wt + 81920;
    unsigned short* w31h = wt + 98304;    unsigned short* w31l = wt + 114688;
    unsigned short* w32h = wt + 131072;   unsigned short* w32l = wt + 147456;

    const long long NH = (long long)N * HID;
    const int blk = 256;
    const unsigned grid_nh2  = (unsigned)((NH / 2 + blk - 1) / blk);
    const unsigned grid_nh   = (unsigned)((NH + blk - 1) / blk);
    const unsigned grid_mfma = (unsigned)((N + 63) / 64);
    const unsigned grid_E    = (unsigned)((E + blk - 1) / blk);
    const unsigned nb_scan   = (unsigned)((N + 255) / 256);
    const unsigned grid_gather = (unsigned)((N + 1) / 2);   // 2 nodes/block, 2 waves/node
    const unsigned grid_gat7 = (unsigned)(((long long)N * 8 + blk - 1) / blk);

    // ---------- W splits (once) ----------
    wsplit<<<64, 256, 0, stream>>>(W12, w12h, w12l);
    wsplit<<<64, 256, 0, stream>>>(W21, w21h, w21l);
    wsplit<<<64, 256, 0, stream>>>(W22, w22h, w22l);
    wsplit<<<64, 256, 0, stream>>>(W31, w31h, w31l);
    wsplit<<<64, 256, 0, stream>>>(W32, w32h, w32l);

    // ---------- build CSR with packed edges ----------
    hipMemsetAsync(icnt, 0, (size_t)N * sizeof(int), stream);
    hist_kernel<<<grid_E, blk, 0, stream>>>(dst, icnt, E);
    scan_block<<<nb_scan, 256, 0, stream>>>(icnt, iexcl, ipart, N);
    scan_partials<<<1, 256, 0, stream>>>(ipart, nb_scan, ioffs, N, E);
    scan_add<<<nb_scan, 256, 0, stream>>>(iexcl, ipart, ioffs, icur, N);
    fill_kernel<<<grid_E, blk, 0, stream>>>(dst, src, ea, icur, epack, E);

    // ---------- layer 1 ----------
    hipMemsetAsync(bnsums, 0, 256 * sizeof(float), stream);
    gather_d7<<<grid_gat7, blk, 0, stream>>>(x, epack, ioffs, We1, be1, buf_agg, N);
    mlp1_fused<false, true><<<grid_mfma, 256, 0, stream>>>(x, buf_agg, W11, b11, w12h, w12l, b12, buf_t, bnsums, N);
    bn_finalize<<<1, 128, 0, stream>>>(bnsums, g1, bt1, bnab, N);
    bn_apply_relu<true><<<grid_nh2, blk, 0, stream>>>(buf_t, bnab, buf_h, h16, NH);

    // ---------- layer 2 ----------
    gather_d128<<<grid_gather, 256, 0, stream>>>(h16, epack, ioffs, We2, be2, buf_h, buf_agg, N);
    hipMemsetAsync(bnsums, 0, 256 * sizeof(float), stream);
    mlp128_fused<false, true><<<grid_mfma, 256, 0, stream>>>(buf_agg, w21h, w21l, b21, w22h, w22l, b22, buf_t, bnsums, N);
    bn_finalize<<<1, 128, 0, stream>>>(bnsums, g2, bt2, bnab, N);
    bn_apply_relu<true><<<grid_nh2, blk, 0, stream>>>(buf_t, bnab, buf_h, h16, NH);

    // ---------- layer 3 ----------
    gather_d128<<<grid_gather, 256, 0, stream>>>(h16, epack, ioffs, We3, be3, buf_h, buf_agg, N);
    hipMemsetAsync(bnsums, 0, 256 * sizeof(float), stream);
    mlp128_fused<false, true><<<grid_mfma, 256, 0, stream>>>(buf_agg, w31h, w31l, b31, w32h, w32l, b32, buf_t, bnsums, N);
    bn_finalize<<<1, 128, 0, stream>>>(bnsums, g3, bt3, bnab, N);

    // ---------- fused BN-apply + pool, then head ----------
    hipMemsetAsync(pools, 0, ((size_t)G * HID + G) * sizeof(float), stream);
    bn_pool<<<grid_nh, blk, 0, stream>>>(buf_t, bnab, batch, pools, cntp, N);
    head_kernel<<<G, 64, 0, stream>>>(pools, cntp, Wf1, bf1, Wf2, bf2, (float*)d_out, G);
}

// Round 16
// 545.611 us; speedup vs baseline: 1.0348x; 1.0348x over previous
//
#include <hip/hip_runtime.h>

#define HID 128

typedef __attribute__((ext_vector_type(8))) short bf16x8;
typedef __attribute__((ext_vector_type(4))) float f32x4;

__device__ inline unsigned short f2bf(float f) {
    unsigned u = __float_as_uint(f);
    unsigned r = (u + 0x7fff + ((u >> 16) & 1)) >> 16;
    return (unsigned short)r;
}
__device__ inline float bf2f(unsigned short b) {
    return __uint_as_float(((unsigned)b) << 16);
}
// split v into trunc-bf16 hi (low 16 bits) + trunc-bf16 lo (high 16 bits)
__device__ inline unsigned packhl(float v) {
    unsigned h = __float_as_uint(v) >> 16;
    float lo = v - __uint_as_float(h << 16);
    unsigned l = __float_as_uint(lo) >> 16;
    return h | (l << 16);
}

// ================= CSR build =================
__global__ void hist_kernel(const int* __restrict__ dst, int* __restrict__ cnt, int E)
{
    int e = blockIdx.x * blockDim.x + threadIdx.x;
    if (e < E) atomicAdd(&cnt[dst[e]], 1);
}

__global__ void scan_block(const int* __restrict__ cnt, int* __restrict__ excl,
                           int* __restrict__ partials, int Nn)
{
    __shared__ int ls[256];
    int i = blockIdx.x * 256 + threadIdx.x;
    int v = (i < Nn) ? cnt[i] : 0;
    ls[threadIdx.x] = v;
    __syncthreads();
    for (int off = 1; off < 256; off <<= 1) {
        int t = (threadIdx.x >= off) ? ls[threadIdx.x - off] : 0;
        __syncthreads();
        ls[threadIdx.x] += t;
        __syncthreads();
    }
    if (i < Nn) excl[i] = ls[threadIdx.x] - v;
    if (threadIdx.x == 255) partials[blockIdx.x] = ls[255];
}

__global__ void scan_partials(int* __restrict__ partials, int nb, int* __restrict__ offsets,
                              int Nn, int E)
{
    __shared__ int ls[256];
    int t = threadIdx.x;
    int v = (t < nb) ? partials[t] : 0;
    ls[t] = v;
    __syncthreads();
    for (int off = 1; off < 256; off <<= 1) {
        int x = (t >= off) ? ls[t - off] : 0;
        __syncthreads();
        ls[t] += x;
        __syncthreads();
    }
    if (t < nb) partials[t] = ls[t] - v;
    if (t == 0) offsets[Nn] = E;
}

__global__ void scan_add(const int* __restrict__ excl, const int* __restrict__ partials,
                         int* __restrict__ offsets, int* __restrict__ cursor, int Nn)
{
    int i = blockIdx.x * 256 + threadIdx.x;
    if (i < Nn) {
        int o = excl[i] + partials[blockIdx.x];
        offsets[i] = o;
        cursor[i] = o;
    }
}

__global__ void fill_kernel(const int* __restrict__ dst, const int* __restrict__ src,
                            const float* __restrict__ ea, int* __restrict__ cursor,
                            float4* __restrict__ epack, int E)
{
    int e = blockIdx.x * blockDim.x + threadIdx.x;
    if (e < E) {
        int pos = atomicAdd(&cursor[dst[e]], 1);
        float4 p;
        p.x = __int_as_float(src[e]);
        p.y = ea[e * 3];
        p.z = ea[e * 3 + 1];
        p.w = ea[e * 3 + 2];
        epack[pos] = p;
    }
}

// ======= W precompute: transpose + hi/lo bf16 split: Wt[n][k] from W[k][n] =======
__global__ void wsplit(const float* __restrict__ W, unsigned short* __restrict__ wh,
                       unsigned short* __restrict__ wl)
{
    int idx = blockIdx.x * 256 + threadIdx.x;
    int n = idx >> 7, k = idx & 127;
    float w = W[k * 128 + n];
    unsigned short h = (unsigned short)(__float_as_uint(w) >> 16);
    float lo = w - bf2f(h);
    unsigned short l = (unsigned short)(__float_as_uint(lo) >> 16);
    wh[idx] = h;
    wl[idx] = l;
}

// ================= layer 1: CSR gather (dim 7) =================
__global__ void gather_d7(const float* __restrict__ x, const float4* __restrict__ epack,
                          const int* __restrict__ offsets,
                          const float* __restrict__ We, const float* __restrict__ be,
                          float* __restrict__ agg, int Nn)
{
    int tid = blockIdx.x * blockDim.x + threadIdx.x;
    int node = tid >> 3;
    int c = tid & 7;
    if (node >= Nn) return;
    float w0 = 0.f, w1 = 0.f, w2 = 0.f, b = 0.f;
    if (c < 7) { w0 = We[c]; w1 = We[7 + c]; w2 = We[14 + c]; b = be[c]; }
    int beg = offsets[node], end = offsets[node + 1];
    float acc = 0.f;
    for (int i = beg; i < end; ++i) {
        float4 ep = epack[i];
        int s = __float_as_int(ep.x);
        float v = b;
        v = fmaf(ep.y, w0, v);
        v = fmaf(ep.z, w1, v);
        v = fmaf(ep.w, w2, v);
        if (c < 7) v += x[s * 7 + c];
        acc += fmaxf(v, 0.f);
    }
    if (c < 7) agg[node * 7 + c] = acc;
}

// ===== layers 2/3: gather, 1 node/wave, 4x unroll with epack group prefetch =====
__global__ void gather_d128(const unsigned short* __restrict__ h16,
                            const float4* __restrict__ epack,
                            const int* __restrict__ offsets,
                            const float* __restrict__ We, const float* __restrict__ be,
                            const float* __restrict__ hprev,
                            float* __restrict__ agg, int Nn)
{
    int node = blockIdx.x * (blockDim.x >> 6) + (threadIdx.x >> 6);
    if (node >= Nn) return;
    int lane = threadIdx.x & 63;
    int beg = offsets[node], end = offsets[node + 1];
    const float2* W2 = (const float2*)We;
    float2 w0 = W2[lane];
    float2 w1 = W2[64 + lane];
    float2 w2 = W2[128 + lane];
    float2 bb = ((const float2*)be)[lane];
    float accx = 0.f, accy = 0.f;

    int i = beg;
    float4 e0, e1, e2, e3;
    if (i + 4 <= end) {
        e0 = epack[i]; e1 = epack[i + 1]; e2 = epack[i + 2]; e3 = epack[i + 3];
    }
    for (; i + 4 <= end; i += 4) {
        // prefetch next group before consuming this group's h16 rows
        float4 f0, f1, f2, f3;
        bool more = (i + 8 <= end);
        if (more) {
            f0 = epack[i + 4]; f1 = epack[i + 5]; f2 = epack[i + 6]; f3 = epack[i + 7];
        }
        ushort2 p0 = ((const ushort2*)(h16 + (size_t)__float_as_int(e0.x) * HID))[lane];
        ushort2 p1 = ((const ushort2*)(h16 + (size_t)__float_as_int(e1.x) * HID))[lane];
        ushort2 p2 = ((const ushort2*)(h16 + (size_t)__float_as_int(e2.x) * HID))[lane];
        ushort2 p3 = ((const ushort2*)(h16 + (size_t)__float_as_int(e3.x) * HID))[lane];
        float vx, vy;
        vx = bb.x + bf2f(p0.x);
        vx = fmaf(e0.y, w0.x, vx); vx = fmaf(e0.z, w1.x, vx); vx = fmaf(e0.w, w2.x, vx);
        vy = bb.y + bf2f(p0.y);
        vy = fmaf(e0.y, w0.y, vy); vy = fmaf(e0.z, w1.y, vy); vy = fmaf(e0.w, w2.y, vy);
        accx += fmaxf(vx, 0.f); accy += fmaxf(vy, 0.f);
        vx = bb.x + bf2f(p1.x);
        vx = fmaf(e1.y, w0.x, vx); vx = fmaf(e1.z, w1.x, vx); vx = fmaf(e1.w, w2.x, vx);
        vy = bb.y + bf2f(p1.y);
        vy = fmaf(e1.y, w0.y, vy); vy = fmaf(e1.z, w1.y, vy); vy = fmaf(e1.w, w2.y, vy);
        accx += fmaxf(vx, 0.f); accy += fmaxf(vy, 0.f);
        vx = bb.x + bf2f(p2.x);
        vx = fmaf(e2.y, w0.x, vx); vx = fmaf(e2.z, w1.x, vx); vx = fmaf(e2.w, w2.x, vx);
        vy = bb.y + bf2f(p2.y);
        vy = fmaf(e2.y, w0.y, vy); vy = fmaf(e2.z, w1.y, vy); vy = fmaf(e2.w, w2.y, vy);
        accx += fmaxf(vx, 0.f); accy += fmaxf(vy, 0.f);
        vx = bb.x + bf2f(p3.x);
        vx = fmaf(e3.y, w0.x, vx); vx = fmaf(e3.z, w1.x, vx); vx = fmaf(e3.w, w2.x, vx);
        vy = bb.y + bf2f(p3.y);
        vy = fmaf(e3.y, w0.y, vy); vy = fmaf(e3.z, w1.y, vy); vy = fmaf(e3.w, w2.y, vy);
        accx += fmaxf(vx, 0.f); accy += fmaxf(vy, 0.f);
        if (more) { e0 = f0; e1 = f1; e2 = f2; e3 = f3; }
    }
    for (; i < end; ++i) {
        float4 ep = epack[i];
        ushort2 hp = ((const ushort2*)(h16 + (size_t)__float_as_int(ep.x) * HID))[lane];
        float vx = bb.x + bf2f(hp.x);
        vx = fmaf(ep.y, w0.x, vx); vx = fmaf(ep.z, w1.x, vx); vx = fmaf(ep.w, w2.x, vx);
        float vy = bb.y + bf2f(hp.y);
        vy = fmaf(ep.y, w0.y, vy); vy = fmaf(ep.z, w1.y, vy); vy = fmaf(ep.w, w2.y, vy);
        accx += fmaxf(vx, 0.f);
        accy += fmaxf(vy, 0.f);
    }
    float2 hv = ((const float2*)(hprev + (size_t)node * HID))[lane];
    float2 outv = {accx + hv.x, accy + hv.y};
    ((float2*)(agg + (size_t)node * HID))[lane] = outv;
}

// ===== MFMA core: acc[2][4] = T(64 rows packed hi/lo) @ Wt for this wave's 32 cols =====
__device__ __forceinline__ void mfma_core(
    const unsigned* T,
    const unsigned short* __restrict__ Wh, const unsigned short* __restrict__ Wl,
    const float* __restrict__ bias,
    int wave, int q, int li, f32x4 (&acc)[2][4])
{
    int ctg0 = wave * 2, ctg1 = wave * 2 + 1;
    float b0 = bias[ctg0 * 16 + li];
    float b1v = bias[ctg1 * 16 + li];
#pragma unroll
    for (int rf = 0; rf < 4; ++rf) {
        acc[0][rf][0] = b0;  acc[0][rf][1] = b0;  acc[0][rf][2] = b0;  acc[0][rf][3] = b0;
        acc[1][rf][0] = b1v; acc[1][rf][1] = b1v; acc[1][rf][2] = b1v; acc[1][rf][3] = b1v;
    }
#pragma unroll
    for (int kb = 0; kb < 4; ++kb) {
        int k0 = kb * 32 + q * 8;
        size_t w0off = (size_t)(ctg0 * 16 + li) * HID + k0;
        size_t w1off = (size_t)(ctg1 * 16 + li) * HID + k0;
        bf16x8 bh0 = *(const bf16x8*)(Wh + w0off);
        bf16x8 bl0 = *(const bf16x8*)(Wl + w0off);
        bf16x8 bh1 = *(const bf16x8*)(Wh + w1off);
        bf16x8 bl1 = *(const bf16x8*)(Wl + w1off);
#pragma unroll
        for (int rf = 0; rf < 4; ++rf) {
            const unsigned* Tp = T + (rf * 16 + li) * 132 + k0;
            uint4 pa = *(const uint4*)Tp;
            uint4 pb = *(const uint4*)(Tp + 4);
            unsigned pv[8] = {pa.x, pa.y, pa.z, pa.w, pb.x, pb.y, pb.z, pb.w};
            bf16x8 ah, al;
#pragma unroll
            for (int j = 0; j < 8; ++j) {
                ah[j] = (short)(pv[j] & 0xffffu);
                al[j] = (short)(pv[j] >> 16);
            }
            acc[0][rf] = __builtin_amdgcn_mfma_f32_16x16x32_bf16(ah, bh0, acc[0][rf], 0, 0, 0);
            acc[0][rf] = __builtin_amdgcn_mfma_f32_16x16x32_bf16(ah, bl0, acc[0][rf], 0, 0, 0);
            acc[0][rf] = __builtin_amdgcn_mfma_f32_16x16x32_bf16(al, bh0, acc[0][rf], 0, 0, 0);
            acc[1][rf] = __builtin_amdgcn_mfma_f32_16x16x32_bf16(ah, bh1, acc[1][rf], 0, 0, 0);
            acc[1][rf] = __builtin_amdgcn_mfma_f32_16x16x32_bf16(ah, bl1, acc[1][rf], 0, 0, 0);
            acc[1][rf] = __builtin_amdgcn_mfma_f32_16x16x32_bf16(al, bh1, acc[1][rf], 0, 0, 0);
        }
    }
}

// global epilogue: write C (+optional relu, +optional BN stats via wave-owned cols)
template <bool RELU, bool STATS>
__device__ __forceinline__ void epilogue_global(
    f32x4 (&acc)[2][4], float* __restrict__ C, float* __restrict__ bnsums,
    float* sls, float* slq, int node0, int wave, int q, int li, int t, int N)
{
#pragma unroll
    for (int ct = 0; ct < 2; ++ct) {
        int colb = (wave * 2 + ct) * 16 + li;
        float sv = 0.f, qv = 0.f;
#pragma unroll
        for (int rf = 0; rf < 4; ++rf) {
#pragma unroll
            for (int r = 0; r < 4; ++r) {
                int n = node0 + rf * 16 + q * 4 + r;
                float v = acc[ct][rf][r];
                if (RELU) v = fmaxf(v, 0.f);
                if (n < N) {
                    C[(size_t)n * HID + colb] = v;
                    if (STATS) { sv += v; qv = fmaf(v, v, qv); }
                }
            }
        }
        if (STATS) {
            sv += __shfl_down(sv, 16); sv += __shfl_down(sv, 32);
            qv += __shfl_down(qv, 16); qv += __shfl_down(qv, 32);
            if (q == 0) { sls[colb] = sv; slq[colb] = qv; }
        }
    }
    if (STATS) {
        __syncthreads();
        if (t < 128) {
            atomicAdd(&bnsums[t], sls[t]);
            atomicAdd(&bnsums[128 + t], slq[t]);
        }
    }
}

// ===== fused MLP layers 2/3 =====
template <bool RELU, bool STATS>
__global__ __launch_bounds__(256) void mlp128_fused(
    const float* __restrict__ A,
    const unsigned short* __restrict__ W1h, const unsigned short* __restrict__ W1l,
    const float* __restrict__ b1,
    const unsigned short* __restrict__ W2h, const unsigned short* __restrict__ W2l,
    const float* __restrict__ b2,
    float* __restrict__ C, float* __restrict__ bnsums, int N)
{
    __shared__ unsigned Ta[64 * 132];
    __shared__ unsigned Tb[64 * 132];
    __shared__ float sls[128], slq[128];
    int t = threadIdx.x;
    int wave = t >> 6, lane = t & 63;
    int q = lane >> 4, li = lane & 15;
    int node0 = blockIdx.x * 64;

    {
        const float4* A4 = (const float4*)(A + (size_t)node0 * HID);
        int rows = N - node0 < 64 ? (N - node0) : 64;
        int limit4 = 32 * rows;
#pragma unroll
        for (int i = 0; i < 8; ++i) {
            int idx = t + i * 256;
            float4 v = {0.f, 0.f, 0.f, 0.f};
            if (idx < limit4) v = A4[idx];
            int row = idx >> 5, c4 = idx & 31;
            uint4 pk;
            pk.x = packhl(v.x); pk.y = packhl(v.y);
            pk.z = packhl(v.z); pk.w = packhl(v.w);
            *(uint4*)(Ta + row * 132 + c4 * 4) = pk;
        }
    }
    __syncthreads();

    {
        f32x4 acc[2][4];
        mfma_core(Ta, W1h, W1l, b1, wave, q, li, acc);
#pragma unroll
        for (int ct = 0; ct < 2; ++ct) {
            int colb = (wave * 2 + ct) * 16 + li;
#pragma unroll
            for (int rf = 0; rf < 4; ++rf) {
#pragma unroll
                for (int r = 0; r < 4; ++r) {
                    float v = fmaxf(acc[ct][rf][r], 0.f);
                    Tb[(rf * 16 + q * 4 + r) * 132 + colb] = packhl(v);
                }
            }
        }
    }
    __syncthreads();

    {
        f32x4 acc[2][4];
        mfma_core(Tb, W2h, W2l, b2, wave, q, li, acc);
        epilogue_global<RELU, STATS>(acc, C, bnsums, sls, slq, node0, wave, q, li, t, N);
    }
}

// ===== fused MLP layer 1 =====
template <bool RELU, bool STATS>
__global__ __launch_bounds__(256) void mlp1_fused(
    const float* __restrict__ x, const float* __restrict__ agg,
    const float* __restrict__ W1, const float* __restrict__ b1,     // [7][128]
    const unsigned short* __restrict__ W2h, const unsigned short* __restrict__ W2l,
    const float* __restrict__ b2,
    float* __restrict__ C, float* __restrict__ bnsums, int N)
{
    __shared__ unsigned Tb[64 * 132];
    __shared__ float sls[128], slq[128];
    int t = threadIdx.x;
    int wave = t >> 6, lane = t & 63;
    int q = lane >> 4, li = lane & 15;
    int node0 = blockIdx.x * 64;

    {
        int row = node0 + wave * 16 + li;
        bool ok = row < N;
        float xa[7];
#pragma unroll
        for (int k = 0; k < 7; ++k) xa[k] = ok ? (x[row * 7 + k] + agg[row * 7 + k]) : 0.f;
        const float4* W14 = (const float4*)W1;
        const float4* b14 = (const float4*)b1;
        unsigned* Trow = Tb + (wave * 16 + li) * 132 + q * 32;
#pragma unroll
        for (int c4 = 0; c4 < 8; ++c4) {
            float4 v = b14[q * 8 + c4];
#pragma unroll
            for (int k = 0; k < 7; ++k) {
                float4 w = W14[k * 32 + q * 8 + c4];
                v.x = fmaf(xa[k], w.x, v.x);
                v.y = fmaf(xa[k], w.y, v.y);
                v.z = fmaf(xa[k], w.z, v.z);
                v.w = fmaf(xa[k], w.w, v.w);
            }
            uint4 pk;
            pk.x = packhl(fmaxf(v.x, 0.f));
            pk.y = packhl(fmaxf(v.y, 0.f));
            pk.z = packhl(fmaxf(v.z, 0.f));
            pk.w = packhl(fmaxf(v.w, 0.f));
            *(uint4*)(Trow + c4 * 4) = pk;
        }
    }
    __syncthreads();

    {
        f32x4 acc[2][4];
        mfma_core(Tb, W2h, W2l, b2, wave, q, li, acc);
        epilogue_global<RELU, STATS>(acc, C, bnsums, sls, slq, node0, wave, q, li, t, N);
    }
}

// ================= BN =================
__global__ void bn_finalize(const float* __restrict__ sums, const float* __restrict__ g,
                            const float* __restrict__ bt, float* __restrict__ ab, int N)
{
    int c = threadIdx.x;
    if (c < 128) {
        float inv = 1.f / (float)N;
        float mu = sums[c] * inv;
        float var = sums[128 + c] * inv - mu * mu;
        float rs = rsqrtf(fmaxf(var, 0.f) + 1e-5f);
        float a = g[c] * rs;
        ab[c] = a;
        ab[128 + c] = bt[c] - a * mu;
    }
}

template <bool W16>
__global__ void bn_apply_relu(const float* __restrict__ h, const float* __restrict__ ab,
                              float* __restrict__ out, unsigned short* __restrict__ h16,
                              long long total)
{
    long long i = ((long long)blockIdx.x * blockDim.x + threadIdx.x) * 2;
    if (i >= total) return;
    int c = (int)(i & 127);
    float2 hv = *(const float2*)(h + i);
    float v0 = fmaxf(fmaf(hv.x, ab[c], ab[128 + c]), 0.f);
    float v1 = fmaxf(fmaf(hv.y, ab[c + 1], ab[129 + c]), 0.f);
    float2 ov = {v0, v1};
    *(float2*)(out + i) = ov;
    if (W16) {
        unsigned pair = (unsigned)f2bf(v0) | ((unsigned)f2bf(v1) << 16);
        *(unsigned*)(h16 + i) = pair;
    }
}

// ================= fused layer-3 BN-apply + mean-pool scatter =================
__global__ void bn_pool(const float* __restrict__ agg, const float* __restrict__ ab,
                        const int* __restrict__ batch,
                        float* __restrict__ pools, float* __restrict__ cnt, int N)
{
    long long i = (long long)blockIdx.x * blockDim.x + threadIdx.x;
    long long total = (long long)N * HID;
    if (i >= total) return;
    int n = (int)(i >> 7);
    int c = (int)(i & 127);
    int g = batch[n];
    float v = fmaxf(fmaf(agg[i], ab[c], ab[128 + c]), 0.f);
    atomicAdd(&pools[(long long)g * HID + c], v);
    if (c == 0) atomicAdd(&cnt[g], 1.f);
}

__global__ void head_kernel(const float* __restrict__ pools, const float* __restrict__ cnt,
                            const float* __restrict__ Wf1, const float* __restrict__ bf1,
                            const float* __restrict__ Wf2, const float* __restrict__ bf2,
                            float* __restrict__ out, int G)
{
    int g = blockIdx.x;
    int t = threadIdx.x;
    __shared__ float p[128];
    float inv = 1.f / fmaxf(cnt[g], 1.f);
    p[t] = pools[g * 128 + t] * inv;
    p[t + 64] = pools[g * 128 + t + 64] * inv;
    __syncthreads();
    float o = bf1[t];
#pragma unroll 8
    for (int k = 0; k < 128; ++k) o = fmaf(p[k], Wf1[k * 64 + t], o);
    o = fmaxf(o, 0.f);
    float prod = o * Wf2[t];
#pragma unroll
    for (int off = 32; off > 0; off >>= 1) prod += __shfl_down(prod, off);
    if (t == 0) out[g] = prod + bf2[0];
}

extern "C" void kernel_launch(void* const* d_in, const int* in_sizes, int n_in,
                              void* d_out, int out_size, void* d_ws, size_t ws_size,
                              hipStream_t stream)
{
    const float* x     = (const float*)d_in[0];
    const float* ea    = (const float*)d_in[1];
    const int*   eidx  = (const int*)d_in[2];
    const int*   batch = (const int*)d_in[3];
    const float* We1 = (const float*)d_in[4];  const float* be1 = (const float*)d_in[5];
    const float* W11 = (const float*)d_in[6];  const float* b11 = (const float*)d_in[7];
    const float* W12 = (const float*)d_in[8];  const float* b12 = (const float*)d_in[9];
    const float* g1  = (const float*)d_in[10]; const float* bt1 = (const float*)d_in[11];
    const float* We2 = (const float*)d_in[12]; const float* be2 = (const float*)d_in[13];
    const float* W21 = (const float*)d_in[14]; const float* b21 = (const float*)d_in[15];
    const float* W22 = (const float*)d_in[16]; const float* b22 = (const float*)d_in[17];
    const float* g2  = (const float*)d_in[18]; const float* bt2 = (const float*)d_in[19];
    const float* We3 = (const float*)d_in[20]; const float* be3 = (const float*)d_in[21];
    const float* W31 = (const float*)d_in[22]; const float* b31 = (const float*)d_in[23];
    const float* W32 = (const float*)d_in[24]; const float* b32 = (const float*)d_in[25];
    const float* g3  = (const float*)d_in[26]; const float* bt3 = (const float*)d_in[27];
    const float* Wf1 = (const float*)d_in[28]; const float* bf1 = (const float*)d_in[29];
    const float* Wf2 = (const float*)d_in[30]; const float* bf2 = (const float*)d_in[31];

    const int N = in_sizes[0] / 7;
    const int E = in_sizes[1] / 3;
    const int G = out_size;
    const int* src = eidx;
    const int* dst = eidx + E;

    float* ws = (float*)d_ws;
    float* buf_h   = ws;                          // N*128
    float* buf_agg = buf_h + (size_t)N * HID;     // N*128
    float* buf_t   = buf_agg + (size_t)N * HID;   // N*128
    float* bnsums  = buf_t + (size_t)N * HID;     // 256
    float* bnab    = bnsums + 256;                // 256
    float* pools   = bnab + 256;                  // G*128
    float* cntp    = pools + (size_t)G * HID;     // G
    float4* epack  = (float4*)(cntp + G);         // E float4
    unsigned short* h16 = (unsigned short*)(epack + E);  // N*128 bf16
    int*   icnt    = (int*)(h16 + (size_t)N * HID); // N
    int*   ioffs   = icnt + N;                    // N+1
    int*   icur    = ioffs + N + 1;               // N
    int*   ipart   = icur + N;                    // 256
    int*   iexcl   = ipart + 256;                 // N
    unsigned short* wt = (unsigned short*)(iexcl + N);  // 5 x 2 x 16384
    unsigned short* w12h = wt;            unsigned short* w12l = wt + 16384;
    unsigned short* w21h = wt + 32768;    unsigned short* w21l = wt + 49152;
    unsigned short* w22h = wt + 65536;    unsigned short* w22l = wt + 81920;
    unsigned short* w31h = wt + 98304;    unsigned short* w31l = wt + 114688;
    unsigned short* w32h = wt + 131072;   unsigned short* w32l = wt + 147456;

    const long long NH = (long long)N * HID;
    const int blk = 256;
    const unsigned grid_nh2  = (unsigned)((NH / 2 + blk - 1) / blk);
    const unsigned grid_nh   = (unsigned)((NH + blk - 1) / blk);
    const unsigned grid_mfma = (unsigned)((N + 63) / 64);
    const unsigned grid_E    = (unsigned)((E + blk - 1) / blk);
    const unsigned nb_scan   = (unsigned)((N + 255) / 256);
    const unsigned grid_gather = (unsigned)((N + 3) / 4);   // 4 waves/block, 1 node/wave
    const unsigned grid_gat7 = (unsigned)(((long long)N * 8 + blk - 1) / blk);

    // ---------- W splits (once) ----------
    wsplit<<<64, 256, 0, stream>>>(W12, w12h, w12l);
    wsplit<<<64, 256, 0, stream>>>(W21, w21h, w21l);
    wsplit<<<64, 256, 0, stream>>>(W22, w22h, w22l);
    wsplit<<<64, 256, 0, stream>>>(W31, w31h, w31l);
    wsplit<<<64, 256, 0, stream>>>(W32, w32h, w32l);

    // ---------- build CSR with packed edges ----------
    hipMemsetAsync(icnt, 0, (size_t)N * sizeof(int), stream);
    hist_kernel<<<grid_E, blk, 0, stream>>>(dst, icnt, E);
    scan_block<<<nb_scan, 256, 0, stream>>>(icnt, iexcl, ipart, N);
    scan_partials<<<1, 256, 0, stream>>>(ipart, nb_scan, ioffs, N, E);
    scan_add<<<nb_scan, 256, 0, stream>>>(iexcl, ipart, ioffs, icur, N);
    fill_kernel<<<grid_E, blk, 0, stream>>>(dst, src, ea, icur, epack, E);

    // ---------- layer 1 ----------
    hipMemsetAsync(bnsums, 0, 256 * sizeof(float), stream);
    gather_d7<<<grid_gat7, blk, 0, stream>>>(x, epack, ioffs, We1, be1, buf_agg, N);
    mlp1_fused<false, true><<<grid_mfma, 256, 0, stream>>>(x, buf_agg, W11, b11, w12h, w12l, b12, buf_t, bnsums, N);
    bn_finalize<<<1, 128, 0, stream>>>(bnsums, g1, bt1, bnab, N);
    bn_apply_relu<true><<<grid_nh2, blk, 0, stream>>>(buf_t, bnab, buf_h, h16, NH);

    // ---------- layer 2 ----------
    gather_d128<<<grid_gather, 256, 0, stream>>>(h16, epack, ioffs, We2, be2, buf_h, buf_agg, N);
    hipMemsetAsync(bnsums, 0, 256 * sizeof(float), stream);
    mlp128_fused<false, true><<<grid_mfma, 256, 0, stream>>>(buf_agg, w21h, w21l, b21, w22h, w22l, b22, buf_t, bnsums, N);
    bn_finalize<<<1, 128, 0, stream>>>(bnsums, g2, bt2, bnab, N);
    bn_apply_relu<true><<<grid_nh2, blk, 0, stream>>>(buf_t, bnab, buf_h, h16, NH);

    // ---------- layer 3 ----------
    gather_d128<<<grid_gather, 256, 0, stream>>>(h16, epack, ioffs, We3, be3, buf_h, buf_agg, N);
    hipMemsetAsync(bnsums, 0, 256 * sizeof(float), stream);
    mlp128_fused<false, true><<<grid_mfma, 256, 0, stream>>>(buf_agg, w31h, w31l, b31, w32h, w32l, b32, buf_t, bnsums, N);
    bn_finalize<<<1, 128, 0, stream>>>(bnsums, g3, bt3, bnab, N);

    // ---------- fused BN-apply + pool, then head ----------
    hipMemsetAsync(pools, 0, ((size_t)G * HID + G) * sizeof(float), stream);
    bn_pool<<<grid_nh, blk, 0, stream>>>(buf_t, bnab, batch, pools, cntp, N);
    head_kernel<<<G, 64, 0, stream>>>(pools, cntp, Wf1, bf1, Wf2, bf2, (float*)d_out, G);
}